// Round 5
// baseline (114.051 us; speedup 1.0000x reference)
//
#include <hip/hip_runtime.h>
#include <hip/hip_bf16.h>

constexpr int NB   = 32;
constexpr int NENV = 8;
constexpr int F0   = 16;
constexpr int F1   = 32;
constexpr int D    = 256;
constexpr int PAIRS = 128 * 64;   // 8192
constexpr float CUT = 5.0f;

typedef float f32x4 __attribute__((ext_vector_type(4)));
typedef short s16x8 __attribute__((ext_vector_type(8)));

__device__ __forceinline__ float fast_rcp(float x) { return __builtin_amdgcn_rcpf(x); }
__device__ __forceinline__ float silu(float a) {
  return a * fast_rcp(1.0f + __expf(-a));
}
__device__ __forceinline__ float fast_tanh(float t) {
  return 1.0f - 2.0f * fast_rcp(__expf(2.0f * t) + 1.0f);
}
// gfx950 single-instruction packed fp32->bf16 (RNE)
__device__ __forceinline__ unsigned int cvt_pk_bf16(float a, float b) {
  unsigned int r;
  asm("v_cvt_pk_bf16_f32 %0, %1, %2" : "=v"(r) : "v"(a), "v"(b));
  return r;
}
__device__ __forceinline__ unsigned short f2bf(float f) {
  return (unsigned short)(cvt_pk_bf16(f, f) & 0xffffu);
}

// ---------------------------------------------------------------------------
// Single-dispatch fused kernel (r14, the session's validated best: 114.47 us,
// absmax 0.09375). One wave per (b,e) pair, 4 pairs/block, 2048 blocks.
//   phase 1: per-neighbor features; lane-halves split the k-range.
//   beta:    (hen @ beta_kernel + bias) * fcut via 4 MFMAs (bias at k=24).
//   phase 2: dual-MFMA (beta@G and inp@d1k replicated, x0.25 pre-scale).
//   tail:    out-GEMM; B-frags built directly from fp32 out_kernel via
//            cvt_pk_bf16 (bit-identical to a prep-kernel path, no ws).
// NOTE: r15-r20 (this and the prior session): EVERY structural deviation from
// this exact body fails deterministically (loop-wrap, prep+ws split,
// module-static weights, added barriers, 8-pair/512-thread restructure with
// statically-verified mappings). The failure is not localizable at source
// level -- treat this body as codegen-fragile; do not restructure without
// disasm diffing a known-good vs perturbed build.
// ---------------------------------------------------------------------------
__global__ __launch_bounds__(256)
__attribute__((amdgpu_waves_per_eu(4, 4)))
void moon_fused(
    const float* __restrict__ r,            // [8192,3]
    const float* __restrict__ r_nb,         // [8192,32,3]
    const float* __restrict__ ee_scales,    // [8]
    const float* __restrict__ ee_kernel,    // [4,16]
    const float* __restrict__ ee_bias,      // [16]
    const float* __restrict__ beta_kernel,  // [24,32]
    const float* __restrict__ beta_bias,    // [32]
    const float* __restrict__ gamma_kernel, // [32,256]
    const float* __restrict__ dense1_kernel,// [4,256]
    const float* __restrict__ dense1_bias,  // [256]
    const float* __restrict__ out_kernel,   // [256,256] (W[k][c], read in tail)
    const float* __restrict__ out_bias,     // [256]
    float* __restrict__ out)                // [8192,256]
{
  __shared__ float s_eek[4 * F0];
  __shared__ float s_eeb[F0];
  __shared__ float s_is2[NENV];
  __shared__ unsigned short s_ghT[4][D * 8];        // [kslot g][d][8] bf16 (16 KB)
  __shared__ unsigned short s_d1kT[D * 8];          // [d][8] bf16 x0.25 (4 KB)
  __shared__ unsigned short s_bkh[4][F1 * 8];       // B-frags of beta_kernel+bias (2 KB)
  __shared__ unsigned short s_hb[4][4][NB * 8];     // [wave][g][row][8]: hen then betah (8 KB)
  __shared__ unsigned short s_inph[4][NB * 8];      // [wave][n][8] bf16 inp A-frag (2 KB)
  __shared__ float s_fcut[4][NB];                   // (0.5 KB)
  __shared__ unsigned short s_resall[4 * 264];      // [pair][264] bf16 res rows (2.1 KB)

  const int tid = threadIdx.x;
  const int w   = tid >> 6;
  const int l   = tid & 63;
  const int be  = blockIdx.x * 4 + w;
  const int be0 = blockIdx.x * 4;

  // ---- staging: small weights ----
  if (tid < 64)       s_eek[tid]      = ee_kernel[tid];
  else if (tid < 80)  s_eeb[tid - 64] = ee_bias[tid - 64];
  else if (tid < 88) { float s = ee_scales[tid - 80]; s_is2[tid - 80] = 1.0f / (s * s); }

  // ---- staging: beta_kernel -> B-frags (k-chunks; bias row at k=24) ----
  if (tid < 128) {
    const int c = tid & 31;
    const int g = tid >> 5;
    unsigned int q[4];
    if (g < 3) {
      float v[8];
      #pragma unroll
      for (int j = 0; j < 8; ++j) v[j] = beta_kernel[(g * 8 + j) * F1 + c];
      q[0] = cvt_pk_bf16(v[0], v[1]); q[1] = cvt_pk_bf16(v[2], v[3]);
      q[2] = cvt_pk_bf16(v[4], v[5]); q[3] = cvt_pk_bf16(v[6], v[7]);
    } else {
      q[0] = cvt_pk_bf16(beta_bias[c], 0.0f); q[1] = 0; q[2] = 0; q[3] = 0;
    }
    *(uint4*)&s_bkh[g][c * 8] = make_uint4(q[0], q[1], q[2], q[3]);
  }

  // ---- staging: gamma -> bf16 transposed, k-chunked (thread t owns row d=t) ----
  {
    const int d = tid;
    unsigned int pk[16];
    #pragma unroll
    for (int k2 = 0; k2 < 16; ++k2)
      pk[k2] = cvt_pk_bf16(gamma_kernel[(2 * k2 + 0) * D + d],
                           gamma_kernel[(2 * k2 + 1) * D + d]);
    #pragma unroll
    for (int g = 0; g < 4; ++g)
      *(uint4*)&s_ghT[g][d * 8] = make_uint4(pk[4*g], pk[4*g+1], pk[4*g+2], pk[4*g+3]);
  }
  // ---- staging: d1kT b-frag, PRE-SCALED by 0.25 (replication cancel; exact) ----
  {
    const int d = tid;
    unsigned int p0 = cvt_pk_bf16(0.25f * dense1_kernel[0 * D + d],
                                  0.25f * dense1_kernel[1 * D + d]);
    unsigned int p1 = cvt_pk_bf16(0.25f * dense1_kernel[2 * D + d],
                                  0.25f * dense1_kernel[3 * D + d]);
    unsigned int p2 = cvt_pk_bf16(0.25f * dense1_bias[d], 0.0f);  // k=4; k=5..7 zero
    *(uint4*)&s_d1kT[d * 8] = make_uint4(p0, p1, p2, 0u);
  }

  __syncthreads();

  const int li = l & 15;          // col-within-tile
  const int g  = l >> 4;          // k-chunk / C-row group

  // ---- phase 1: per-neighbor features -> s_hb (hen role), s_inph, s_fcut ----
  {
    const int n    = l & 31;
    const int half = l >> 5;     // k-range split
    float rx = r[be * 3 + 0];
    float ry = r[be * 3 + 1];
    float rz = r[be * 3 + 2];
    const float* rn = r_nb + (be * NB + n) * 3;
    float dx = rn[0] - rx;
    float dy = rn[1] - ry;
    float dz = rn[2] - rz;
    float d2 = dx * dx + dy * dy + dz * dz;
    float dist = sqrtf(d2);
    float feats[4] = {dist, dx, dy, dz};
    float h[8];
    #pragma unroll
    for (int j8 = 0; j8 < 8; ++j8) {
      int j = half * 8 + j8;
      float t = s_eeb[j];
      #pragma unroll
      for (int i = 0; i < 4; ++i) t += feats[i] * s_eek[i * F0 + j];
      h[j8] = fast_tanh(t);
    }
    unsigned int hp0 = cvt_pk_bf16(h[0], h[1]);
    unsigned int hp1 = cvt_pk_bf16(h[2], h[3]);
    unsigned int hp2 = cvt_pk_bf16(h[4], h[5]);
    unsigned int hp3 = cvt_pk_bf16(h[6], h[7]);
    if (half == 0) {
      *(uint4*)&s_hb[w][0][n * 8] = make_uint4(hp0, hp1, hp2, hp3);
      *(uint4*)&s_hb[w][3][n * 8] = make_uint4(0x3F80u, 0u, 0u, 0u);
      float lp  = log1pf(dist);
      float inv = lp / dist;
      unsigned int q0 = cvt_pk_bf16(lp, dx * inv);
      unsigned int q1 = cvt_pk_bf16(dy * inv, dz * inv);
      *(uint4*)&s_inph[w][n * 8] = make_uint4(q0, q1, 0x3F80u, 0u);
    } else {
      *(uint4*)&s_hb[w][1][n * 8] = make_uint4(hp0, hp1, hp2, hp3);
      float env[NENV];
      #pragma unroll
      for (int s = 0; s < NENV; ++s) env[s] = __expf(-d2 * s_is2[s]);
      unsigned int e0 = cvt_pk_bf16(env[0], env[1]);
      unsigned int e1 = cvt_pk_bf16(env[2], env[3]);
      unsigned int e2 = cvt_pk_bf16(env[4], env[5]);
      unsigned int e3 = cvt_pk_bf16(env[6], env[7]);
      *(uint4*)&s_hb[w][2][n * 8] = make_uint4(e0, e1, e2, e3);
      float xc = dist * (1.0f / CUT);
      s_fcut[w][n] = (xc < 1.0f)
                   ? 0.5f * (__cosf(3.14159265358979323846f * xc) + 1.0f)
                   : 0.0f;
    }
  }

  // ---- beta via MFMA: beta[n][c] = (hen @ bk + bias) * fcut[n] (wave-local) ----
  {
    s16x8 ah0 = *(const s16x8*)&s_hb[w][g][(0 * 16 + li) * 8];
    s16x8 ah1 = *(const s16x8*)&s_hb[w][g][(1 * 16 + li) * 8];
    s16x8 bb0 = *(const s16x8*)&s_bkh[g][(0 * 16 + li) * 8];
    s16x8 bb1 = *(const s16x8*)&s_bkh[g][(1 * 16 + li) * 8];
    f32x4 z = {0.f, 0.f, 0.f, 0.f};
    f32x4 c00 = __builtin_amdgcn_mfma_f32_16x16x32_bf16(ah0, bb0, z, 0, 0, 0);
    f32x4 c01 = __builtin_amdgcn_mfma_f32_16x16x32_bf16(ah0, bb1, z, 0, 0, 0);
    f32x4 c10 = __builtin_amdgcn_mfma_f32_16x16x32_bf16(ah1, bb0, z, 0, 0, 0);
    f32x4 c11 = __builtin_amdgcn_mfma_f32_16x16x32_bf16(ah1, bb1, z, 0, 0, 0);
    const int cl = li >> 3;
    const int sl = li & 7;
    #pragma unroll
    for (int reg = 0; reg < 4; ++reg) {
      int row0 = g * 4 + reg;
      int row1 = 16 + g * 4 + reg;
      float fc0 = s_fcut[w][row0];
      float fc1 = s_fcut[w][row1];
      s_hb[w][cl    ][row0 * 8 + sl] = f2bf(c00[reg] * fc0);
      s_hb[w][2 + cl][row0 * 8 + sl] = f2bf(c01[reg] * fc0);
      s_hb[w][cl    ][row1 * 8 + sl] = f2bf(c10[reg] * fc1);
      s_hb[w][2 + cl][row1 * 8 + sl] = f2bf(c11[reg] * fc1);
    }
  }

  // ---- phase 2: c = beta@G, f = inp@d1k+b (replicated x0.25); reduce ----
  {
    s16x8 a0 = *(const s16x8*)&s_hb[w][g][(0 * 16 + li) * 8];
    s16x8 a1 = *(const s16x8*)&s_hb[w][g][(1 * 16 + li) * 8];
    s16x8 ai0 = *(const s16x8*)&s_inph[w][(0 * 16 + li) * 8];
    s16x8 ai1 = *(const s16x8*)&s_inph[w][(1 * 16 + li) * 8];

    #pragma unroll 4
    for (int nt = 0; nt < 16; ++nt) {
      const int d = nt * 16 + li;
      s16x8 b  = *(const s16x8*)&s_ghT[g][d * 8];
      s16x8 bd = *(const s16x8*)&s_d1kT[d * 8];
      f32x4 z = {0.f, 0.f, 0.f, 0.f};
      f32x4 c0 = __builtin_amdgcn_mfma_f32_16x16x32_bf16(a0, b, z, 0, 0, 0);
      f32x4 c1 = __builtin_amdgcn_mfma_f32_16x16x32_bf16(a1, b, z, 0, 0, 0);
      f32x4 f0 = __builtin_amdgcn_mfma_f32_16x16x32_bf16(ai0, bd, z, 0, 0, 0);
      f32x4 f1 = __builtin_amdgcn_mfma_f32_16x16x32_bf16(ai1, bd, z, 0, 0, 0);
      float pv = 0.f;
      #pragma unroll
      for (int reg = 0; reg < 4; ++reg) {
        pv += silu(f0[reg]) * c0[reg];
        pv += silu(f1[reg]) * c1[reg];
      }
      pv += __shfl_xor(pv, 16);
      pv += __shfl_xor(pv, 32);
      if (g == (nt & 3)) s_resall[w * 264 + nt * 16 + li] = f2bf(pv);
    }
  }
  __syncthreads();   // all 4 pairs' res rows needed by every wave in the tail

  // ---- tail: out[be0+0..3, :] = silu(res @ W + b). B-frags built directly
  //      from fp32 out_kernel: slot j of (ks,nt) = bf16(W[ks*32+g*8+j][c]),
  //      c = col0 + nt*16 + li. ----
  {
    const int col0 = w * 64;
    float bi[4];
    #pragma unroll
    for (int nt = 0; nt < 4; ++nt) bi[nt] = out_bias[col0 + nt * 16 + li];

    f32x4 acc[4] = {{0.f,0.f,0.f,0.f},{0.f,0.f,0.f,0.f},{0.f,0.f,0.f,0.f},{0.f,0.f,0.f,0.f}};
    const unsigned short* arow = &s_resall[(li & 3) * 264 + g * 8];
    const float* wp = out_kernel + col0 + li;   // lane's base column

    #pragma unroll 2
    for (int ks = 0; ks < 8; ++ks) {
      s16x8 a = *(const s16x8*)(arow + ks * 32);
      const float* wk0 = wp + (ks * 32 + g * 8) * D;   // W[k0][c0]
      #pragma unroll
      for (int nt = 0; nt < 4; ++nt) {
        const float* wq = wk0 + nt * 16;
        union { s16x8 v; unsigned int u[4]; } ub;
        #pragma unroll
        for (int jj = 0; jj < 4; ++jj)
          ub.u[jj] = cvt_pk_bf16(wq[(2 * jj) * D], wq[(2 * jj + 1) * D]);
        acc[nt] = __builtin_amdgcn_mfma_f32_16x16x32_bf16(a, ub.v, acc[nt], 0, 0, 0);
      }
    }
    if (g == 0) {
      #pragma unroll
      for (int nt = 0; nt < 4; ++nt) {
        #pragma unroll
        for (int reg = 0; reg < 4; ++reg) {
          out[(be0 + reg) * D + col0 + nt * 16 + li] = silu(acc[nt][reg] + bi[nt]);
        }
      }
    }
  }
}

extern "C" void kernel_launch(void* const* d_in, const int* in_sizes, int n_in,
                              void* d_out, int out_size, void* d_ws, size_t ws_size,
                              hipStream_t stream) {
  const float* r            = (const float*)d_in[0];
  const float* r_nb         = (const float*)d_in[1];
  const float* ee_scales    = (const float*)d_in[2];
  const float* ee_kernel    = (const float*)d_in[3];
  const float* ee_bias      = (const float*)d_in[4];
  const float* beta_kernel  = (const float*)d_in[5];
  const float* beta_bias    = (const float*)d_in[6];
  const float* gamma_kernel = (const float*)d_in[7];
  const float* dense1_kernel= (const float*)d_in[8];
  const float* dense1_bias  = (const float*)d_in[9];
  const float* out_kernel   = (const float*)d_in[10];
  const float* out_bias     = (const float*)d_in[11];
  float* out = (float*)d_out;

  // single dispatch; d_ws unused
  hipLaunchKernelGGL(moon_fused, dim3(PAIRS / 4), dim3(256), 0, stream,
                     r, r_nb, ee_scales, ee_kernel, ee_bias,
                     beta_kernel, beta_bias, gamma_kernel,
                     dense1_kernel, dense1_bias, out_kernel, out_bias, out);
}